// Round 13
// baseline (1640.140 us; speedup 1.0000x reference)
//
#include <hip/hip_runtime.h>
#include <cfloat>
#include <cstdint>

#define NB 32
#define NPTS 1024
#define KNN 20
#define RTOT (NB * NPTS)

typedef __attribute__((ext_vector_type(8))) short bf16x8;
typedef __attribute__((ext_vector_type(4))) float f32x4;

__device__ __forceinline__ float lrelu(float v) { return v >= 0.f ? v : 0.2f * v; }

// ================= split-bf16 helpers =================
__device__ __forceinline__ void split2(float x, ushort& h, ushort& l) {
    uint u = __float_as_uint(x);
    uint r = u + 0x7FFFu + ((u >> 16) & 1u);
    ushort hh = (ushort)(r >> 16);
    float hf = __uint_as_float((uint)hh << 16);
    float d = x - hf;
    uint u2 = __float_as_uint(d);
    uint r2 = u2 + 0x7FFFu + ((u2 >> 16) & 1u);
    h = hh;
    l = (ushort)(r2 >> 16);
}

__device__ __forceinline__ uint pack2(ushort a, ushort b) { return (uint)a | ((uint)b << 16); }

__device__ __forceinline__ void stage_split8(const float* __restrict__ g,
                                             ushort* __restrict__ dh, ushort* __restrict__ dl) {
    float4 a = *(const float4*)(g);
    float4 b = *(const float4*)(g + 4);
    float xs[8] = {a.x, a.y, a.z, a.w, b.x, b.y, b.z, b.w};
    ushort h[8], l[8];
#pragma unroll
    for (int i = 0; i < 8; ++i) split2(xs[i], h[i], l[i]);
    uint4 H, L;
    H.x = pack2(h[0], h[1]); H.y = pack2(h[2], h[3]);
    H.z = pack2(h[4], h[5]); H.w = pack2(h[6], h[7]);
    L.x = pack2(l[0], l[1]); L.y = pack2(l[2], l[3]);
    L.z = pack2(l[4], l[5]); L.w = pack2(l[6], l[7]);
    *(uint4*)(dh) = H;
    *(uint4*)(dl) = L;
}

// ---------------- prep: transpose x | split W5 | zero sums arena (one dispatch) ----------------
__global__ void k_prep(const float* __restrict__ x, float* __restrict__ xT,
                       const float* __restrict__ W5, ushort* __restrict__ W5h,
                       ushort* __restrict__ W5l, float* __restrict__ sumsA) {
    int bid = blockIdx.x;
    if (bid < 384) {
        int g = bid * 256 + threadIdx.x;
        int n = g % NPTS;
        int c = (g / NPTS) % 3;
        int b = g / (3 * NPTS);
        xT[((size_t)b * NPTS + n) * 3 + c] = x[g];
    } else if (bid < 704) {
        int g = ((bid - 384) * 256 + threadIdx.x) * 8;
        stage_split8(W5 + g, W5h + g, W5l + g);
    } else {
        for (int i = threadIdx.x; i < 2048 * 5; i += 256) sumsA[i] = 0.f;
    }
}

// ---------------- 64x64 GEMM (small convs): H[r,o] = sum_k X[r,k]*W[o,k] ----------------
__global__ __launch_bounds__(256) void k_gemm_xwt(
    const float* __restrict__ X, int ldx, int K,
    const float* __restrict__ W,
    float* __restrict__ H, int ldh)
{
    __shared__ float As[16][68];
    __shared__ float Bs[16][68];
    int tid = threadIdx.x;
    int tx = tid & 15, ty = tid >> 4;
    int c0 = blockIdx.x * 64;
    int r0 = blockIdx.y * 64;
    float acc[4][4] = {};
    int lr = tid >> 4, lk = tid & 15;
    for (int k0 = 0; k0 < K; k0 += 16) {
#pragma unroll
        for (int i = 0; i < 4; ++i) {
            int row = lr + i * 16;
            int kk = k0 + lk;
            float av = 0.f, bv = 0.f;
            if (kk < K) {
                av = X[(size_t)(r0 + row) * ldx + kk];
                bv = W[(size_t)(c0 + row) * K + kk];
            }
            As[lk][row] = av;
            Bs[lk][row] = bv;
        }
        __syncthreads();
#pragma unroll
        for (int k = 0; k < 16; ++k) {
            float4 a4 = *(const float4*)&As[k][ty * 4];
            float4 b4 = *(const float4*)&Bs[k][tx * 4];
            float av[4] = {a4.x, a4.y, a4.z, a4.w};
            float bv[4] = {b4.x, b4.y, b4.z, b4.w};
#pragma unroll
            for (int i = 0; i < 4; ++i)
#pragma unroll
                for (int j = 0; j < 4; ++j)
                    acc[i][j] = fmaf(av[i], bv[j], acc[i][j]);
        }
        __syncthreads();
    }
#pragma unroll
    for (int i = 0; i < 4; ++i) {
        float4 v = make_float4(acc[i][0], acc[i][1], acc[i][2], acc[i][3]);
        *(float4*)&H[(size_t)(r0 + ty * 4 + i) * ldh + c0 + tx * 4] = v;
    }
}

// tile order: 28 off-diagonal tiles first, 8 diagonal tiles last (cheap blocks in the tail)
__constant__ int pd_tile_order[36] = {
    1, 2, 3, 4, 5, 6, 7,
    9, 10, 11, 12, 13, 14,
    16, 17, 18, 19, 20,
    22, 23, 24, 25,
    27, 28, 29,
    31, 32,
    34,
    0, 8, 15, 21, 26, 30, 33, 35
};

// ------- symmetric batched pd with fused xx, upper-triangle blocks, 128x128 / 8x8 -------
// Mirror tile staged through LDS (reusing As/Bs) so stores are coalesced 128B runs.
// Values bit-identical to the direct-store version (same arithmetic, same addresses).
template<int K>
__global__ __launch_bounds__(256) void k_pd_sym(
    const float* __restrict__ X, int ldx, float* __restrict__ pd)
{
    __shared__ float S[32 * 132];            // As rows 0..15 | Bs rows 16..31; reused as T[32][132]
    __shared__ float sxr[128], sxc[128];
    float (*As)[132] = (float(*)[132])S;
    float (*Bs)[132] = (float(*)[132])(S + 16 * 132);
    int b = blockIdx.x & 31;
    int t = pd_tile_order[blockIdx.x >> 5];
    int tid = threadIdx.x;
    int tx = tid & 15, ty = tid >> 4;
    int rb = 0, rem = 8;
    while (t >= rem) { t -= rem; ++rb; --rem; }
    int cb = rb + t;
    int r0 = rb * 128, c0 = cb * 128;
    const float* Xb = X + (size_t)b * NPTS * ldx;
    {
        int rr = (tid < 128) ? (r0 + tid) : (c0 + tid - 128);
        const float* p = Xb + (size_t)rr * ldx;
        float s = 0.f;
#pragma unroll 8
        for (int c = 0; c < K; ++c) { float v = p[c]; s += v * v; }
        if (tid < 128) sxr[tid] = s; else sxc[tid - 128] = s;
    }
    int lk = tid & 15, lr = tid >> 4;
    float acc[8][8] = {};
    for (int k0 = 0; k0 < K; k0 += 16) {
#pragma unroll
        for (int i = 0; i < 8; ++i) {
            int row = lr + i * 16;
            int kk = k0 + lk;
            float av = 0.f, bv = 0.f;
            if (kk < K) {
                av = Xb[(size_t)(r0 + row) * ldx + kk];
                bv = Xb[(size_t)(c0 + row) * ldx + kk];
            }
            As[lk][row] = av;
            Bs[lk][row] = bv;
        }
        __syncthreads();
#pragma unroll
        for (int k = 0; k < 16; ++k) {
            float a[8], bb[8];
            *(float4*)&a[0]  = *(const float4*)&As[k][ty * 4];
            *(float4*)&a[4]  = *(const float4*)&As[k][64 + ty * 4];
            *(float4*)&bb[0] = *(const float4*)&Bs[k][tx * 4];
            *(float4*)&bb[4] = *(const float4*)&Bs[k][64 + tx * 4];
#pragma unroll
            for (int i = 0; i < 8; ++i)
#pragma unroll
                for (int j = 0; j < 8; ++j)
                    acc[i][j] = fmaf(a[i], bb[j], acc[i][j]);
        }
        __syncthreads();
    }
    float* pdb = pd + (size_t)b * NPTS * NPTS;
    float xc[8];
#pragma unroll
    for (int j = 0; j < 8; ++j)
        xc[j] = sxc[(j < 4) ? (tx * 4 + j) : (64 + tx * 4 + j - 4)];
    float xr[8];
#pragma unroll
    for (int i = 0; i < 8; ++i)
        xr[i] = sxr[(i < 4) ? (ty * 4 + i) : (64 + ty * 4 + i - 4)];
    // normal tile: coalesced direct store
#pragma unroll
    for (int i = 0; i < 8; ++i) {
        int r = r0 + ((i < 4) ? (ty * 4 + i) : (64 + ty * 4 + i - 4));
        float* orow = &pdb[(size_t)r * NPTS + c0];
        float4 v0, v1;
        v0.x = 2.f * acc[i][0] - xr[i] - xc[0];
        v0.y = 2.f * acc[i][1] - xr[i] - xc[1];
        v0.z = 2.f * acc[i][2] - xr[i] - xc[2];
        v0.w = 2.f * acc[i][3] - xr[i] - xc[3];
        v1.x = 2.f * acc[i][4] - xr[i] - xc[4];
        v1.y = 2.f * acc[i][5] - xr[i] - xc[5];
        v1.z = 2.f * acc[i][6] - xr[i] - xc[6];
        v1.w = 2.f * acc[i][7] - xr[i] - xc[7];
        *(float4*)&orow[tx * 4]      = v0;
        *(float4*)&orow[64 + tx * 4] = v1;
    }
    // mirror tile (cb > rb): LDS-transpose then coalesced store, 4 chunks of 32 rows
    if (cb > rb) {
        float (*T)[132] = (float(*)[132])S;
        int row = tid >> 3;                  // 0..31
        int cbase = (tid & 7) * 16;          // float col base of this thread's 4 float4s
#pragma unroll
        for (int ch = 0; ch < 4; ++ch) {
            __syncthreads();                 // prior chunk reads (or K-loop) done before overwrite
            if ((tx >> 3) == (ch & 1)) {
                int jlo = (ch >> 1) * 4;
                int txl = tx & 7;
#pragma unroll
                for (int jj = 0; jj < 4; ++jj) {
                    int j = jlo + jj;
                    int cl = txl * 4 + jj;
#pragma unroll
                    for (int i = 0; i < 8; ++i) {
                        int rr = (i < 4) ? (ty * 4 + i) : (64 + ty * 4 + i - 4);
                        T[cl][rr] = 2.f * acc[i][j] - xc[j] - xr[i];
                    }
                }
            }
            __syncthreads();
            float* orow = &pdb[(size_t)(c0 + ch * 32 + row) * NPTS + r0];
#pragma unroll
            for (int u = 0; u < 4; ++u) {
                int col = cbase + u * 4;
                *(float4*)&orow[col] = *(float4*)&T[row][col];
            }
        }
    }
}

// ---------------- wave-per-2-rows top-k (k=20), ILP over two independent reduce chains ----------------
__global__ __launch_bounds__(256) void k_topk_wave(const float* __restrict__ pd, int* __restrict__ idx) {
    int w = (blockIdx.x * 256 + threadIdx.x) >> 6;   // wave id in [0, RTOT/2)
    int lane = threadIdx.x & 63;
    const float* row0 = pd + (size_t)(2 * w) * NPTS;
    const float* row1 = row0 + NPTS;
    float v0[16], v1[16];
#pragma unroll
    for (int j = 0; j < 16; ++j) { v0[j] = row0[lane + 64 * j]; v1[j] = row1[lane + 64 * j]; }
    float bv0 = v0[0], bv1 = v1[0];
    int bj0 = 0, bj1 = 0;
#pragma unroll
    for (int j = 1; j < 16; ++j) {
        if (v0[j] > bv0) { bv0 = v0[j]; bj0 = j; }
        if (v1[j] > bv1) { bv1 = v1[j]; bj1 = j; }
    }
    int* out0 = idx + (size_t)(2 * w) * KNN;
    int* out1 = out0 + KNN;
    for (int kk = 0; kk < KNN; ++kk) {
        float cv0 = bv0, cv1 = bv1;
        int ci0 = lane + (bj0 << 6), ci1 = lane + (bj1 << 6);
#pragma unroll
        for (int s = 1; s < 64; s <<= 1) {
            float ov0 = __shfl_xor(cv0, s);
            int oi0 = __shfl_xor(ci0, s);
            float ov1 = __shfl_xor(cv1, s);
            int oi1 = __shfl_xor(ci1, s);
            if (ov0 > cv0 || (ov0 == cv0 && oi0 < ci0)) { cv0 = ov0; ci0 = oi0; }
            if (ov1 > cv1 || (ov1 == cv1 && oi1 < ci1)) { cv1 = ov1; ci1 = oi1; }
        }
        if (lane == 0) { out0[kk] = ci0; out1[kk] = ci1; }
        bool mine0 = (ci0 & 63) == lane;
        bool mine1 = (ci1 & 63) == lane;
        int jd0 = ci0 >> 6, jd1 = ci1 >> 6;
#pragma unroll
        for (int j = 0; j < 16; ++j) {
            if (mine0 && j == jd0) v0[j] = -FLT_MAX;
            if (mine1 && j == jd1) v1[j] = -FLT_MAX;
        }
        bv0 = v0[0]; bj0 = 0; bv1 = v1[0]; bj1 = 0;
#pragma unroll
        for (int j = 1; j < 16; ++j) {
            if (v0[j] > bv0) { bv0 = v0[j]; bj0 = j; }
            if (v1[j] > bv1) { bv1 = v1[j]; bj1 = j; }
        }
    }
}

// conv5 GEMM: 128x256 block tile, 512 threads = 8 waves (2x4) of 64x64,
// mfma_f32_16x16x32_bf16, 3-pass hi/lo. XCD-chunked grid. BN stats fused.
#define LDK 40
__global__ __launch_bounds__(512) void k_gemm5_mfma(
    const float* __restrict__ X, const ushort* __restrict__ Wh, const ushort* __restrict__ Wl,
    float* __restrict__ H, float* __restrict__ sums)
{
    __shared__ __align__(16) ushort sAh[128 * LDK];
    __shared__ __align__(16) ushort sAl[128 * LDK];
    __shared__ __align__(16) ushort sBh[256 * LDK];
    __shared__ __align__(16) ushort sBl[256 * LDK];
    int tid = threadIdx.x;
    int lane = tid & 63, w = tid >> 6;
    int wm = w >> 2, wn = w & 3;
    int bid = blockIdx.x;
    int wg = (bid & 7) * 128 + (bid >> 3);
    int cb = wg & 3, rb = wg >> 2;
    int r0 = rb * 128, c0 = cb * 256;
    int srA = tid >> 2, skA = (tid & 3) * 8;
    int srB = tid >> 1, skB = (tid & 1) * 16;
    int fr = lane & 15;
    int kg = (lane >> 4) << 3;
    f32x4 acc[4][4] = {};
    for (int k0 = 0; k0 < 640; k0 += 32) {
        stage_split8(X + (size_t)(r0 + srA) * 640 + k0 + skA,
                     &sAh[srA * LDK + skA], &sAl[srA * LDK + skA]);
        {
            size_t gb = (size_t)(c0 + srB) * 640 + k0 + skB;
            *(uint4*)&sBh[srB * LDK + skB]     = *(const uint4*)(Wh + gb);
            *(uint4*)&sBh[srB * LDK + skB + 8] = *(const uint4*)(Wh + gb + 8);
            *(uint4*)&sBl[srB * LDK + skB]     = *(const uint4*)(Wl + gb);
            *(uint4*)&sBl[srB * LDK + skB + 8] = *(const uint4*)(Wl + gb + 8);
        }
        __syncthreads();
        bf16x8 ah[4], al[4];
#pragma unroll
        for (int mi = 0; mi < 4; ++mi) {
            int rr = wm * 64 + mi * 16 + fr;
            ah[mi] = *(const bf16x8*)&sAh[rr * LDK + kg];
            al[mi] = *(const bf16x8*)&sAl[rr * LDK + kg];
        }
#pragma unroll
        for (int ni = 0; ni < 4; ++ni) {
            int cc = wn * 64 + ni * 16 + fr;
            bf16x8 bh = *(const bf16x8*)&sBh[cc * LDK + kg];
            bf16x8 bl = *(const bf16x8*)&sBl[cc * LDK + kg];
#pragma unroll
            for (int mi = 0; mi < 4; ++mi) {
                acc[mi][ni] = __builtin_amdgcn_mfma_f32_16x16x32_bf16(ah[mi], bh, acc[mi][ni], 0, 0, 0);
                acc[mi][ni] = __builtin_amdgcn_mfma_f32_16x16x32_bf16(ah[mi], bl, acc[mi][ni], 0, 0, 0);
                acc[mi][ni] = __builtin_amdgcn_mfma_f32_16x16x32_bf16(al[mi], bh, acc[mi][ni], 0, 0, 0);
            }
        }
        __syncthreads();
    }
#pragma unroll
    for (int mi = 0; mi < 4; ++mi) {
        int rg = r0 + wm * 64 + mi * 16 + (lane >> 4) * 4;
#pragma unroll
        for (int ni = 0; ni < 4; ++ni) {
            int cg = c0 + wn * 64 + ni * 16 + fr;
#pragma unroll
            for (int r = 0; r < 4; ++r)
                H[(size_t)(rg + r) * 1024 + cg] = acc[mi][ni][r];
        }
    }
    float* csum  = (float*)sAh;
    float* csum2 = csum + 256;
    if (tid < 256) { csum[tid] = 0.f; csum2[tid] = 0.f; }
    __syncthreads();
#pragma unroll
    for (int ni = 0; ni < 4; ++ni) {
        float s = 0.f, s2 = 0.f;
#pragma unroll
        for (int mi = 0; mi < 4; ++mi)
#pragma unroll
            for (int r = 0; r < 4; ++r) { float v = acc[mi][ni][r]; s += v; s2 += v * v; }
        int c = wn * 64 + ni * 16 + fr;
        atomicAdd(&csum[c], s);
        atomicAdd(&csum2[c], s2);
    }
    __syncthreads();
    if (tid < 256) {
        atomicAdd(&sums[c0 + tid], csum[tid]);
        atomicAdd(&sums[1024 + c0 + tid], csum2[tid]);
    }
}

// ---------------- BN stats (conv1-4) ----------------
__global__ __launch_bounds__(256) void k_bn_stats(const float* __restrict__ H, int ldh, int O, int R,
                                                  float* __restrict__ sums) {
    int nblk = gridDim.x;
    int rows = (R + nblk - 1) / nblk;
    int r0 = blockIdx.x * rows;
    int r1 = r0 + rows; if (r1 > R) r1 = R;
    int tid = threadIdx.x;
    int per = 256 / O;
    int c = tid % O;
    int rOff = tid / O;
    float s = 0.f, s2 = 0.f;
    for (int r = r0 + rOff; r < r1; r += per) {
        float v = H[(size_t)r * ldh + c];
        s += v; s2 += v * v;
    }
    __shared__ float ls[256], ls2[256];
    ls[tid] = s; ls2[tid] = s2;
    __syncthreads();
    for (int st = 128; st >= O; st >>= 1) {
        if (tid < st) { ls[tid] += ls[tid + st]; ls2[tid] += ls2[tid + st]; }
        __syncthreads();
    }
    if (tid < O) {
        atomicAdd(&sums[c], ls[tid]);
        atomicAdd(&sums[O + c], ls2[tid]);
    }
}

// ---------------- graph_feature with fused BN finalize ----------------
__global__ __launch_bounds__(256) void k_graph_feature(
    const float* __restrict__ hT, int ldh, int C,
    const int* __restrict__ idx, const float* __restrict__ sums,
    const float* __restrict__ g, const float* __restrict__ bta, float invR,
    float* __restrict__ out, int ldo, int colOff)
{
    __shared__ float sss[256];
    int tid = threadIdx.x;
    if (tid < C) {
        float mu = sums[tid] * invR;
        float var = sums[C + tid] * invR - mu * mu;
        float sc = g[tid] / sqrtf(var + 1e-5f);
        sss[tid] = sc;
        sss[C + tid] = bta[tid] - mu * sc;
    }
    __syncthreads();
    int ppb = 256 / C;
    int p = tid / C;
    int c = tid % C;
    int r = blockIdx.x * ppb + p;
    int b = r >> 10;
    float sc = sss[c], sh = sss[C + c];
    float self = hT[(size_t)r * ldh + c];
    float vs = lrelu(sc * self + sh);
    const int* ip = idx + (size_t)r * KNN;
    float m = -FLT_MAX;
#pragma unroll 4
    for (int k = 0; k < KNN; ++k) {
        int j = ip[k];
        float hv = hT[((size_t)b * NPTS + j) * ldh + c];
        float v = lrelu(sc * hv + sh);
        m = fmaxf(m, v);
    }
    float* orow = out + (size_t)r * ldo + colOff;
    orow[c] = vs;
    orow[C + c] = m - vs;
}

// ---------------- channel max for conv5 with fused BN finalize; 8 rows/block ----------------
__global__ __launch_bounds__(256) void k_chanmax(const float* __restrict__ h5,
                                                 const float* __restrict__ sums,
                                                 const float* __restrict__ g,
                                                 const float* __restrict__ bta, float invR,
                                                 float* __restrict__ feat) {
    __shared__ float sls[2048];
    __shared__ float red[256];
    int tid = threadIdx.x;
    for (int o = tid; o < 1024; o += 256) {
        float mu = sums[o] * invR;
        float var = sums[1024 + o] * invR - mu * mu;
        float sc = g[o] / sqrtf(var + 1e-5f);
        sls[o] = sc;
        sls[1024 + o] = bta[o] - mu * sc;
    }
    __syncthreads();
    for (int rr = 0; rr < 8; ++rr) {
        int r = blockIdx.x * 8 + rr;
        const float* rowp = h5 + (size_t)r * 1024;
        float m = -FLT_MAX;
        for (int o = tid; o < 1024; o += 256) {
            float v = lrelu(sls[o] * rowp[o] + sls[1024 + o]);
            m = fmaxf(m, v);
        }
        red[tid] = m;
        __syncthreads();
        for (int s = 128; s > 0; s >>= 1) {
            if (tid < s) red[tid] = fmaxf(red[tid], red[tid + s]);
            __syncthreads();
        }
        if (tid == 0) feat[r] = red[0];
        __syncthreads();
    }
}

// ---------------- fused FC + BN1d + lrelu: 8 channels x 32 batches per block ----------------
__global__ __launch_bounds__(256) void k_fc_bn(
    const float* __restrict__ in, const float* __restrict__ Lw, const float* __restrict__ bias,
    const float* __restrict__ g, const float* __restrict__ bta,
    float* __restrict__ out, int K, int J)
{
    int tid = threadIdx.x;
    int b = tid & 31, jj = tid >> 5;
    int j = blockIdx.x * 8 + jj;
    const float* xr = in + (size_t)b * K;
    const float* wr = Lw + (size_t)j * K;
    float acc = 0.f;
    for (int k = 0; k < K; ++k) acc = fmaf(xr[k], wr[k], acc);
    if (bias) acc += bias[j];
    __shared__ float lh[8][33];
    __shared__ float lsc[8], lsh[8];
    lh[jj][b] = acc;
    __syncthreads();
    if (b == 0) {
        float s = 0.f, s2 = 0.f;
        for (int bb = 0; bb < 32; ++bb) { float v = lh[jj][bb]; s += v; s2 += v * v; }
        float mu = s / 32.f;
        float var = s2 / 32.f - mu * mu;
        float sc = g[j] / sqrtf(var + 1e-5f);
        lsc[jj] = sc;
        lsh[jj] = bta[j] - mu * sc;
    }
    __syncthreads();
    out[(size_t)b * J + j] = lrelu(lsc[jj] * acc + lsh[jj]);
}

// ---------------- final FC (no BN) ----------------
__global__ void k_fc(const float* __restrict__ in, const float* __restrict__ Lw,
                     const float* __restrict__ bias, float* __restrict__ out, int K, int J) {
    int g = blockIdx.x * 256 + threadIdx.x;
    if (g >= 32 * J) return;
    int b = g / J, j = g % J;
    const float* xr = in + (size_t)b * K;
    const float* wr = Lw + (size_t)j * K;
    float acc = 0.f;
    for (int k = 0; k < K; ++k) acc = fmaf(xr[k], wr[k], acc);
    out[g] = bias ? acc + bias[j] : acc;
}

extern "C" void kernel_launch(void* const* d_in, const int* in_sizes, int n_in,
                              void* d_out, int out_size, void* d_ws, size_t ws_size,
                              hipStream_t stream) {
    const float* x   = (const float*)d_in[0];
    const float* W1  = (const float*)d_in[1];
    const float* g1  = (const float*)d_in[2];
    const float* b1  = (const float*)d_in[3];
    const float* W2  = (const float*)d_in[4];
    const float* g2  = (const float*)d_in[5];
    const float* b2  = (const float*)d_in[6];
    const float* W3  = (const float*)d_in[7];
    const float* g3  = (const float*)d_in[8];
    const float* b3  = (const float*)d_in[9];
    const float* W4  = (const float*)d_in[10];
    const float* g4  = (const float*)d_in[11];
    const float* b4  = (const float*)d_in[12];
    const float* W5  = (const float*)d_in[13];
    const float* g5  = (const float*)d_in[14];
    const float* b5  = (const float*)d_in[15];
    const float* L1  = (const float*)d_in[16];
    const float* g6  = (const float*)d_in[17];
    const float* b6  = (const float*)d_in[18];
    const float* L2  = (const float*)d_in[19];
    const float* bl2 = (const float*)d_in[20];
    const float* g7  = (const float*)d_in[21];
    const float* b7  = (const float*)d_in[22];
    const float* L3  = (const float*)d_in[23];
    const float* bl3 = (const float*)d_in[24];

    float* ws = (float*)d_ws;
    size_t off = 0;
    auto alloc = [&](size_t n) { size_t o = off; off += (n + 63) & ~(size_t)63; return o; };
    float* pd   = ws + alloc((size_t)NB * NPTS * NPTS);  // 134 MB, aliased with h5
    float* h5   = pd;
    float* xcT  = ws + alloc((size_t)RTOT * 640);
    float* hbuf = ws + alloc((size_t)RTOT * 128);
    float* xT   = ws + alloc((size_t)RTOT * 3);
    float* sumsA = ws + alloc(2048 * 5);
    float* feat = ws + alloc(RTOT);
    float* h1   = ws + alloc(32 * 512);
    float* h2   = ws + alloc(32 * 256);
    int*   idxb = (int*)(ws + alloc((size_t)RTOT * KNN));
    ushort* W5h = (ushort*)(ws + alloc(1024 * 640 / 2));
    ushort* W5l = (ushort*)(ws + alloc(1024 * 640 / 2));
    const float invR = 1.f / RTOT;

    k_prep<<<705, 256, 0, stream>>>(x, xT, W5, W5h, W5l, sumsA);

    auto run_knn = [&](const float* X, int ldx, int C) {
        if (C == 3)
            k_pd_sym<3><<<36 * NB, 256, 0, stream>>>(X, ldx, pd);
        else
            k_pd_sym<128><<<36 * NB, 256, 0, stream>>>(X, ldx, pd);
        k_topk_wave<<<RTOT / 8, 256, 0, stream>>>(pd, idxb);
    };
    auto run_conv = [&](const float* X, int ldx, int K, const float* W, int O, float* sums) {
        k_gemm_xwt<<<dim3(O / 64, RTOT / 64), 256, 0, stream>>>(X, ldx, K, W, hbuf, O);
        k_bn_stats<<<256, 256, 0, stream>>>(hbuf, O, O, RTOT, sums);
    };
    auto run_gf = [&](int C, int colOff, const float* sums, const float* g, const float* bta) {
        int ppb = 256 / C;
        k_graph_feature<<<RTOT / ppb, 256, 0, stream>>>(hbuf, C, C, idxb, sums, g, bta, invR,
                                                        xcT, 640, colOff);
    };

    // stage 1
    run_knn(xT, 3, 3);
    run_conv(xT, 3, 3, W1, 64, sumsA);
    run_gf(64, 0, sumsA, g1, b1);

    // stage 2
    run_knn(xcT + 0, 640, 128);
    run_conv(xcT + 0, 640, 128, W2, 64, sumsA + 2048);
    run_gf(64, 128, sumsA + 2048, g2, b2);

    // stage 3
    run_knn(xcT + 128, 640, 128);
    run_conv(xcT + 128, 640, 128, W3, 64, sumsA + 4096);
    run_gf(64, 256, sumsA + 4096, g3, b3);

    // stage 4
    run_knn(xcT + 256, 640, 128);
    run_conv(xcT + 256, 640, 128, W4, 128, sumsA + 6144);
    run_gf(128, 384, sumsA + 6144, g4, b4);

    // conv5 (BN stats fused) + chan-max (BN finalize fused)
    float* sums5 = sumsA + 8192;
    k_gemm5_mfma<<<1024, 512, 0, stream>>>(xcT, W5h, W5l, h5, sums5);
    k_chanmax<<<RTOT / 8, 256, 0, stream>>>(h5, sums5, g5, b5, invR, feat);

    // FC head
    k_fc_bn<<<64, 256, 0, stream>>>(feat, L1, nullptr, g6, b6, h1, 1024, 512);
    k_fc_bn<<<32, 256, 0, stream>>>(h1, L2, bl2, g7, b7, h2, 512, 256);
    k_fc<<<(32 * 40 + 255) / 256, 256, 0, stream>>>(h2, L3, bl3, (float*)d_out, 256, 40);
}